// Round 1
// baseline (127.358 us; speedup 1.0000x reference)
//
#include <hip/hip_runtime.h>
#include <float.h>

#define NCNT 33   // count classes 0..32
#define NPTS 32   // max poles/zeros

// ---------- DPP helpers ----------
template<int CTRL, bool BC>
__device__ __forceinline__ int dpp_i(int old, int v) {
    return __builtin_amdgcn_update_dpp(old, v, CTRL, 0xF, 0xF, BC);
}

// full-wave (64) sum; result broadcast to all lanes via readlane 63
__device__ __forceinline__ float wave_sum63(float v) {
    v += __int_as_float(dpp_i<0x111, true>(0, __float_as_int(v))); // row_shr:1
    v += __int_as_float(dpp_i<0x112, true>(0, __float_as_int(v))); // row_shr:2
    v += __int_as_float(dpp_i<0x114, true>(0, __float_as_int(v))); // row_shr:4
    v += __int_as_float(dpp_i<0x118, true>(0, __float_as_int(v))); // row_shr:8
    v += __int_as_float(dpp_i<0x142, true>(0, __float_as_int(v))); // row_bcast:15
    v += __int_as_float(dpp_i<0x143, true>(0, __float_as_int(v))); // row_bcast:31
    return __int_as_float(__builtin_amdgcn_readlane(__float_as_int(v), 63));
}

// full-wave max + first-index argmax; results broadcast (uniform)
__device__ __forceinline__ void wave_argmax(float v, int idx, float& maxv, int& maxi) {
    float cv = v; int ci = idx;
#define AM_STEP(C)                                                                   \
    {                                                                                \
        float ov = __int_as_float(dpp_i<C, false>(__float_as_int(cv), __float_as_int(cv))); \
        int   oi = dpp_i<C, false>(ci, ci);                                          \
        bool take = (ov > cv) || (ov == cv && oi < ci);                              \
        cv = take ? ov : cv;                                                         \
        ci = take ? oi : ci;                                                         \
    }
    AM_STEP(0x111) AM_STEP(0x112) AM_STEP(0x114) AM_STEP(0x118) AM_STEP(0x142) AM_STEP(0x143)
#undef AM_STEP
    maxv = __int_as_float(__builtin_amdgcn_readlane(__float_as_int(cv), 63));
    maxi = __builtin_amdgcn_readlane(ci, 63);
}

// ---------- main kernel: one wave per (row, part) unit ----------
__global__ __launch_bounds__(256) void vltf_kernel(
    const float* __restrict__ pole_logits, const float* __restrict__ zero_logits,
    const float* __restrict__ poles_all,   const float* __restrict__ zeros_all,
    const float* __restrict__ tpoles,      const float* __restrict__ tzeros,
    const int* __restrict__ tnum_p,        const int* __restrict__ tnum_z,
    float* __restrict__ partials)
{
    // per-wave LDS slice: [0..63] sanitized tgt pts, 16B pad, [68..131] sanitized pred pts
    __shared__ __align__(16) float lds[4][136];
    __shared__ float acc[4];

    const int wid  = threadIdx.x >> 6;
    const int lane = threadIdx.x & 63;
    const int unit = blockIdx.x * 4 + wid;
    const int row  = unit >> 1;
    const int part = unit & 1;

    const float* logits = part ? zero_logits : pole_logits;
    const float* predp  = part ? zeros_all   : poles_all;
    const float* tgtp   = part ? tzeros      : tpoles;
    const int*   tnum   = part ? tnum_z      : tnum_p;

    // ---- cross-entropy + argmax over 33 logits (lanes 0..32 active) ----
    float x  = (lane < NCNT) ? logits[row * NCNT + lane] : -FLT_MAX;
    int   xi = (lane < NCNT) ? lane : 1000;
    float vmax; int np;
    wave_argmax(x, xi, vmax, np);                 // np = pred count (uniform)
    float e = (lane < NCNT) ? __expf(x - vmax) : 0.f;
    float sume = wave_sum63(e);
    const int nt = tnum[row];                     // target count (uniform, scalar load)
    float xt = __int_as_float(__builtin_amdgcn_readlane(__float_as_int(x), nt));
    float nll = vmax + __logf(sume) - xt;

    // ---- load own point; stage sanitized copy for the other half ----
    const bool isPred = lane < 32;
    const int  idx    = lane & 31;
    const float2* ownArr = (const float2*)(isPred ? predp : tgtp);
    const float2  Pt     = ownArr[row * NPTS + idx];
    const int  nown = isPred ? np : nt;
    const bool vown = idx < nown;
    float* myl = &lds[wid][0];
    {
        float2* wr = (float2*)(myl + (isPred ? 68 : 0));  // pred -> 68, tgt -> 0
        wr[idx] = make_float2(vown ? Pt.x : 1e15f, vown ? Pt.y : 1e15f);
    }
    __syncthreads();   // make each wave's staged points visible (cheap, once)

    // ---- chamfer: each lane min over 32 "other" points (broadcast float4 reads) ----
    const float4* ov = (const float4*)(myl + (isPred ? 0 : 68)); // pred lanes read tgt, tgt lanes read pred
    float m = FLT_MAX;
#pragma unroll
    for (int i = 0; i < 16; ++i) {
        float4 o = ov[i];
        float dx0 = Pt.x - o.x, dy0 = Pt.y - o.y;
        float dx1 = Pt.x - o.z, dy1 = Pt.y - o.w;
        float d0 = dx0 * dx0 + dy0 * dy0;
        float d1 = dx1 * dx1 + dy1 * dy1;
        m = fminf(fminf(m, d0), d1);              // v_min3_f32
    }

    // ---- per-lane term with wave-uniform special cases ----
    float T;
    if (np > 0 && nt > 0) {
        T = vown ? (m / (float)nown) : 0.f;       // mean_p2t + mean_t2p in one sum
    } else if (np == 0 && nt == 0) {
        T = 0.f;
    } else if (np == 0) {                          // out = sum_tgt_sq
        T = (!isPred && vown) ? (Pt.x * Pt.x + Pt.y * Pt.y) : 0.f;
    } else {                                       // nt == 0 -> sum_pred_sq
        T = (isPred && vown) ? (Pt.x * Pt.x + Pt.y * Pt.y) : 0.f;
    }
    float cham = wave_sum63(T);

    float unitv = 5.f * nll + cham;
    if (lane == 0) acc[wid] = unitv;
    __syncthreads();
    if (threadIdx.x == 0)
        partials[blockIdx.x] = acc[0] + acc[1] + acc[2] + acc[3];
}

// ---------- finalize: sum 16384 partials, divide by B ----------
__global__ __launch_bounds__(256) void vltf_finalize(
    const float* __restrict__ partials, int n, float invB, float* __restrict__ out)
{
    float s = 0.f;
    for (int i = threadIdx.x; i < n; i += 256) s += partials[i];
    s = wave_sum63(s);
    __shared__ float sh[4];
    if ((threadIdx.x & 63) == 0) sh[threadIdx.x >> 6] = s;
    __syncthreads();
    if (threadIdx.x == 0) out[0] = (sh[0] + sh[1] + sh[2] + sh[3]) * invB;
}

extern "C" void kernel_launch(void* const* d_in, const int* in_sizes, int n_in,
                              void* d_out, int out_size, void* d_ws, size_t ws_size,
                              hipStream_t stream) {
    const float* pole_logits = (const float*)d_in[0];
    const float* zero_logits = (const float*)d_in[1];
    const float* poles_all   = (const float*)d_in[2];
    const float* zeros_all   = (const float*)d_in[3];
    const float* tpoles      = (const float*)d_in[4];
    const float* tzeros      = (const float*)d_in[5];
    const int*   tnp         = (const int*)d_in[6];
    const int*   tnz         = (const int*)d_in[7];

    const int B      = in_sizes[6];      // 32768
    const int units  = 2 * B;            // (row, part) units
    const int blocks = units / 4;        // 4 waves (units) per 256-thread block

    float* partials = (float*)d_ws;      // blocks * 4 bytes (64 KiB) of scratch

    vltf_kernel<<<blocks, 256, 0, stream>>>(pole_logits, zero_logits,
                                            poles_all, zeros_all,
                                            tpoles, tzeros, tnp, tnz, partials);
    vltf_finalize<<<1, 256, 0, stream>>>(partials, blocks, 1.0f / (float)B,
                                         (float*)d_out);
}

// Round 2
// 113.657 us; speedup vs baseline: 1.1205x; 1.1205x over previous
//
#include <hip/hip_runtime.h>
#include <float.h>

#define NCNT 33   // count classes 0..32
#define NPTS 32   // max poles/zeros

// ---------- DPP helpers ----------
template<int CTRL, bool BC>
__device__ __forceinline__ int dpp_i(int old, int v) {
    return __builtin_amdgcn_update_dpp(old, v, CTRL, 0xF, 0xF, BC);
}

// full-wave (64) sum; result broadcast to all lanes via readlane 63
__device__ __forceinline__ float wave_sum63(float v) {
    v += __int_as_float(dpp_i<0x111, true>(0, __float_as_int(v))); // row_shr:1
    v += __int_as_float(dpp_i<0x112, true>(0, __float_as_int(v))); // row_shr:2
    v += __int_as_float(dpp_i<0x114, true>(0, __float_as_int(v))); // row_shr:4
    v += __int_as_float(dpp_i<0x118, true>(0, __float_as_int(v))); // row_shr:8
    v += __int_as_float(dpp_i<0x142, true>(0, __float_as_int(v))); // row_bcast:15
    v += __int_as_float(dpp_i<0x143, true>(0, __float_as_int(v))); // row_bcast:31
    return __int_as_float(__builtin_amdgcn_readlane(__float_as_int(v), 63));
}

// full-wave max; result broadcast (uniform). bound_ctrl=false + old=v so
// out-of-range source lanes contribute fmax(v,v)=v.
__device__ __forceinline__ float wave_max63(float v) {
#define MX_STEP(C)                                                                    \
    {                                                                                 \
        int o = dpp_i<C, false>(__float_as_int(v), __float_as_int(v));                \
        v = fmaxf(v, __int_as_float(o));                                              \
    }
    MX_STEP(0x111) MX_STEP(0x112) MX_STEP(0x114) MX_STEP(0x118) MX_STEP(0x142) MX_STEP(0x143)
#undef MX_STEP
    return __int_as_float(__builtin_amdgcn_readlane(__float_as_int(v), 63));
}

// ---------- main kernel: one wave per (row, part) unit ----------
__global__ __launch_bounds__(256) void vltf_kernel(
    const float* __restrict__ pole_logits, const float* __restrict__ zero_logits,
    const float* __restrict__ poles_all,   const float* __restrict__ zeros_all,
    const float* __restrict__ tpoles,      const float* __restrict__ tzeros,
    const int* __restrict__ tnum_p,        const int* __restrict__ tnum_z,
    float* __restrict__ partials)
{
    // per-wave LDS slice: [0..63] sanitized tgt pts, 16B pad, [68..131] sanitized pred pts
    __shared__ __align__(16) float lds[4][136];
    __shared__ float acc[4];

    // readfirstlane -> compiler-provably wave-uniform: scalarizes row/part/pointer math
    const int wid  = __builtin_amdgcn_readfirstlane(threadIdx.x >> 6);
    const int lane = threadIdx.x & 63;
    const int unit = blockIdx.x * 4 + wid;
    const int row  = unit >> 1;
    const int part = unit & 1;

    const float* logits = part ? zero_logits : pole_logits;
    const float* predp  = part ? zeros_all   : poles_all;
    const float* tgtp   = part ? tzeros      : tpoles;
    const int*   tnum   = part ? tnum_z      : tnum_p;

    // ---- cross-entropy + argmax over 33 logits (lanes 0..32 active) ----
    float x = (lane < NCNT) ? logits[row * NCNT + lane] : -FLT_MAX;
    float vmax = wave_max63(x);
    unsigned long long bm = __ballot(lane < NCNT && x == vmax);
    const int np = (int)__builtin_ctzll(bm);      // first-max index == pred count (uniform)
    float e = (lane < NCNT) ? __expf(x - vmax) : 0.f;
    float sume = wave_sum63(e);
    const int nt = tnum[row];                     // target count (uniform -> s_load)
    float xt = __int_as_float(__builtin_amdgcn_readlane(__float_as_int(x), nt));
    float nll = vmax + __logf(sume) - xt;

    // ---- load own point; stage sanitized copy for the other half ----
    const bool isPred = lane < 32;
    const int  idx    = lane & 31;
    const float2* ownArr = (const float2*)(isPred ? predp : tgtp);
    const float2  Pt     = ownArr[row * NPTS + idx];
    const int  nown = isPred ? np : nt;
    const bool vown = idx < nown;
    float* myl = &lds[wid][0];
    {
        float2* wr = (float2*)(myl + (isPred ? 68 : 0));  // pred -> 68, tgt -> 0
        wr[idx] = make_float2(vown ? Pt.x : 1e15f, vown ? Pt.y : 1e15f);
    }
    __syncthreads();   // make each wave's staged points visible

    // ---- chamfer: each lane min over 32 "other" points (broadcast float4 reads) ----
    const float4* ov = (const float4*)(myl + (isPred ? 0 : 68)); // pred lanes read tgt, tgt lanes read pred
    float m = FLT_MAX;
#pragma unroll
    for (int i = 0; i < 16; ++i) {
        float4 o = ov[i];
        float dx0 = Pt.x - o.x, dy0 = Pt.y - o.y;
        float dx1 = Pt.x - o.z, dy1 = Pt.y - o.w;
        float d0 = dx0 * dx0 + dy0 * dy0;
        float d1 = dx1 * dx1 + dy1 * dy1;
        m = fminf(fminf(m, d0), d1);              // v_min3_f32
    }

    // ---- per-lane term with wave-uniform special cases ----
    float T;
    if (np > 0 && nt > 0) {
        T = vown ? (m / (float)nown) : 0.f;       // mean_p2t + mean_t2p in one sum
    } else if (np == 0 && nt == 0) {
        T = 0.f;
    } else if (np == 0) {                          // out = sum_tgt_sq
        T = (!isPred && vown) ? (Pt.x * Pt.x + Pt.y * Pt.y) : 0.f;
    } else {                                       // nt == 0 -> sum_pred_sq
        T = (isPred && vown) ? (Pt.x * Pt.x + Pt.y * Pt.y) : 0.f;
    }
    float cham = wave_sum63(T);

    float unitv = 5.f * nll + cham;
    if (lane == 0) acc[wid] = unitv;
    __syncthreads();
    if (threadIdx.x == 0)
        partials[blockIdx.x] = acc[0] + acc[1] + acc[2] + acc[3];
}

// ---------- finalize: sum 16384 partials (as 4096 float4), divide by B ----------
__global__ __launch_bounds__(256) void vltf_finalize(
    const float4* __restrict__ p4, int n4, float invB, float* __restrict__ out)
{
    float s = 0.f;
    for (int i = threadIdx.x; i < n4; i += 256) {
        float4 v = p4[i];
        s += (v.x + v.y) + (v.z + v.w);
    }
    s = wave_sum63(s);
    __shared__ float sh[4];
    if ((threadIdx.x & 63) == 0) sh[threadIdx.x >> 6] = s;
    __syncthreads();
    if (threadIdx.x == 0) out[0] = (sh[0] + sh[1] + sh[2] + sh[3]) * invB;
}

extern "C" void kernel_launch(void* const* d_in, const int* in_sizes, int n_in,
                              void* d_out, int out_size, void* d_ws, size_t ws_size,
                              hipStream_t stream) {
    const float* pole_logits = (const float*)d_in[0];
    const float* zero_logits = (const float*)d_in[1];
    const float* poles_all   = (const float*)d_in[2];
    const float* zeros_all   = (const float*)d_in[3];
    const float* tpoles      = (const float*)d_in[4];
    const float* tzeros      = (const float*)d_in[5];
    const int*   tnp         = (const int*)d_in[6];
    const int*   tnz         = (const int*)d_in[7];

    const int B      = in_sizes[6];      // 32768
    const int units  = 2 * B;            // (row, part) units
    const int blocks = units / 4;        // 4 waves (units) per 256-thread block

    float* partials = (float*)d_ws;      // blocks * 4 bytes (64 KiB) of scratch

    vltf_kernel<<<blocks, 256, 0, stream>>>(pole_logits, zero_logits,
                                            poles_all, zeros_all,
                                            tpoles, tzeros, tnp, tnz, partials);
    vltf_finalize<<<1, 256, 0, stream>>>((const float4*)partials, blocks / 4,
                                         1.0f / (float)B, (float*)d_out);
}

// Round 3
// 110.236 us; speedup vs baseline: 1.1553x; 1.0310x over previous
//
#include <hip/hip_runtime.h>
#include <float.h>

#define NCNT 33   // count classes 0..32
#define NPTS 32   // max poles/zeros

typedef float f32x2 __attribute__((ext_vector_type(2)));

__device__ __forceinline__ f32x2 mk2(float a, float b) { f32x2 r; r.x = a; r.y = b; return r; }

// ---------- DPP helpers ----------
template<int CTRL, bool BC>
__device__ __forceinline__ int dpp_i(int old, int v) {
    return __builtin_amdgcn_update_dpp(old, v, CTRL, 0xF, 0xF, BC);
}

// full-wave (64) sum; result broadcast to all lanes via readlane 63
__device__ __forceinline__ float wave_sum63(float v) {
    v += __int_as_float(dpp_i<0x111, true>(0, __float_as_int(v))); // row_shr:1
    v += __int_as_float(dpp_i<0x112, true>(0, __float_as_int(v))); // row_shr:2
    v += __int_as_float(dpp_i<0x114, true>(0, __float_as_int(v))); // row_shr:4
    v += __int_as_float(dpp_i<0x118, true>(0, __float_as_int(v))); // row_shr:8
    v += __int_as_float(dpp_i<0x142, true>(0, __float_as_int(v))); // row_bcast:15
    v += __int_as_float(dpp_i<0x143, true>(0, __float_as_int(v))); // row_bcast:31
    return __int_as_float(__builtin_amdgcn_readlane(__float_as_int(v), 63));
}

// full-wave max; result broadcast (uniform). bound_ctrl=false + old=v so
// out-of-range source lanes contribute fmax(v,v)=v.
__device__ __forceinline__ float wave_max63(float v) {
#define MX_STEP(C)                                                                    \
    {                                                                                 \
        int o = dpp_i<C, false>(__float_as_int(v), __float_as_int(v));                \
        v = fmaxf(v, __int_as_float(o));                                              \
    }
    MX_STEP(0x111) MX_STEP(0x112) MX_STEP(0x114) MX_STEP(0x118) MX_STEP(0x142) MX_STEP(0x143)
#undef MX_STEP
    return __int_as_float(__builtin_amdgcn_readlane(__float_as_int(v), 63));
}

// ---------- main kernel: one wave per (row, part) unit ----------
// LDS slice per wave (floats): tgt UV [0..63], tgt S [64..95], pred UV [96..159], pred S [160..191]
// UV layout: float4 j = (u_{2j}, u_{2j+1}, v_{2j}, v_{2j+1}); u=-2x, v=-2y, s=|pt|^2 (1e30 if invalid)
__global__ __launch_bounds__(256) void vltf_kernel(
    const float* __restrict__ pole_logits, const float* __restrict__ zero_logits,
    const float* __restrict__ poles_all,   const float* __restrict__ zeros_all,
    const float* __restrict__ tpoles,      const float* __restrict__ tzeros,
    const int* __restrict__ tnum_p,        const int* __restrict__ tnum_z,
    float* __restrict__ partials)
{
    __shared__ __align__(16) float lds[4][192];

    const int wid  = __builtin_amdgcn_readfirstlane(threadIdx.x >> 6);
    const int lane = threadIdx.x & 63;
    const int unit = blockIdx.x * 4 + wid;
    const int row  = unit >> 1;
    const int part = unit & 1;

    const float* logits = part ? zero_logits : pole_logits;
    const float* predp  = part ? zeros_all   : poles_all;
    const float* tgtp   = part ? tzeros      : tpoles;
    const int*   tnum   = part ? tnum_z      : tnum_p;

    // ---- cross-entropy + argmax over 33 logits (lanes 0..32 active) ----
    float x = (lane < NCNT) ? logits[row * NCNT + lane] : -FLT_MAX;
    float vmax = wave_max63(x);
    unsigned long long bm = __ballot(lane < NCNT && x == vmax);
    const int np = (int)__builtin_ctzll(bm);      // first-max index == pred count (uniform)
    float e = (lane < NCNT) ? __expf(x - vmax) : 0.f;
    float sume = wave_sum63(e);
    const int nt = tnum[row];                     // target count (uniform)
    float xt = __int_as_float(__builtin_amdgcn_readlane(__float_as_int(x), nt));
    float nll = vmax + __logf(sume) - xt;

    // ---- load own point; stage (u,v,s) for the other half ----
    const bool isPred = lane < 32;
    const int  idx    = lane & 31;
    const float2* ownArr = (const float2*)(isPred ? predp : tgtp);
    const float2  Pt     = ownArr[row * NPTS + idx];
    const int  nown = isPred ? np : nt;
    const bool vown = idx < nown;
    const float sreal = fmaf(Pt.x, Pt.x, Pt.y * Pt.y);

    float* myl = &lds[wid][0];
    const int wbase = isPred ? 96 : 0;
    const int uvpos = wbase + ((idx >> 1) << 2) + (idx & 1);
    myl[uvpos]          = vown ? -2.f * Pt.x : 0.f;
    myl[uvpos + 2]      = vown ? -2.f * Pt.y : 0.f;
    myl[wbase + 64 + idx] = vown ? sreal : 1e30f;
    __syncthreads();

    // ---- chamfer: min over 32 "other" points, 4 points/iter via pk_fma ----
    const int rbase = isPred ? 0 : 96;            // pred lanes read tgt staging, tgt lanes read pred
    const float4* UVo = (const float4*)(myl + rbase);
    const float4* So  = (const float4*)(myl + rbase + 64);
    const f32x2 Pxv = mk2(Pt.x, Pt.x);
    const f32x2 Pyv = mk2(Pt.y, Pt.y);
    float m = FLT_MAX;
#pragma unroll
    for (int i = 0; i < 8; ++i) {
        float4 uv0 = UVo[2 * i], uv1 = UVo[2 * i + 1];
        float4 s4  = So[i];
        f32x2 val0 = Pyv * mk2(uv0.z, uv0.w) + mk2(s4.x, s4.y);
        val0       = Pxv * mk2(uv0.x, uv0.y) + val0;
        f32x2 val1 = Pyv * mk2(uv1.z, uv1.w) + mk2(s4.z, s4.w);
        val1       = Pxv * mk2(uv1.x, uv1.y) + val1;
        m = fminf(m, fminf(val0.x, val0.y));      // v_min3_f32
        m = fminf(m, fminf(val1.x, val1.y));
    }

    // ---- per-lane term with wave-uniform special cases ----
    float T;
    if (np > 0 && nt > 0) {
        T = vown ? (m + sreal) / (float)nown : 0.f;   // |p|^2 folded in once
    } else if (np == 0 && nt == 0) {
        T = 0.f;
    } else if (np == 0) {                              // out = sum_tgt_sq
        T = (!isPred && vown) ? sreal : 0.f;
    } else {                                           // nt == 0 -> sum_pred_sq
        T = (isPred && vown) ? sreal : 0.f;
    }
    float cham = wave_sum63(T);

    if (lane == 0) partials[unit] = 5.f * nll + cham;  // one store per wave, no 2nd barrier
}

// ---------- finalize: sum 65536 partials (as 16384 float4), divide by B ----------
__global__ __launch_bounds__(1024) void vltf_finalize(
    const float4* __restrict__ p4, int n4, float invB, float* __restrict__ out)
{
    float s = 0.f;
    for (int i = threadIdx.x; i < n4; i += 1024) {
        float4 v = p4[i];
        s += (v.x + v.y) + (v.z + v.w);
    }
    s = wave_sum63(s);
    __shared__ float sh[16];
    if ((threadIdx.x & 63) == 0) sh[threadIdx.x >> 6] = s;
    __syncthreads();
    if (threadIdx.x == 0) {
        float t = 0.f;
#pragma unroll
        for (int i = 0; i < 16; ++i) t += sh[i];
        out[0] = t * invB;
    }
}

extern "C" void kernel_launch(void* const* d_in, const int* in_sizes, int n_in,
                              void* d_out, int out_size, void* d_ws, size_t ws_size,
                              hipStream_t stream) {
    const float* pole_logits = (const float*)d_in[0];
    const float* zero_logits = (const float*)d_in[1];
    const float* poles_all   = (const float*)d_in[2];
    const float* zeros_all   = (const float*)d_in[3];
    const float* tpoles      = (const float*)d_in[4];
    const float* tzeros      = (const float*)d_in[5];
    const int*   tnp         = (const int*)d_in[6];
    const int*   tnz         = (const int*)d_in[7];

    const int B      = in_sizes[6];      // 32768
    const int units  = 2 * B;            // (row, part) units
    const int blocks = units / 4;        // 4 waves (units) per 256-thread block

    float* partials = (float*)d_ws;      // units * 4 bytes (256 KiB) of scratch

    vltf_kernel<<<blocks, 256, 0, stream>>>(pole_logits, zero_logits,
                                            poles_all, zeros_all,
                                            tpoles, tzeros, tnp, tnz, partials);
    vltf_finalize<<<1, 1024, 0, stream>>>((const float4*)partials, units / 4,
                                          1.0f / (float)B, (float*)d_out);
}

// Round 4
// 108.276 us; speedup vs baseline: 1.1762x; 1.0181x over previous
//
#include <hip/hip_runtime.h>
#include <float.h>

#define NCNT 33   // count classes 0..32
#define NPTS 32   // max poles/zeros

typedef float f32x2 __attribute__((ext_vector_type(2)));

__device__ __forceinline__ f32x2 mk2(float a, float b) { f32x2 r; r.x = a; r.y = b; return r; }

// ---------- DPP helpers ----------
template<int CTRL, bool BC>
__device__ __forceinline__ int dpp_i(int old, int v) {
    return __builtin_amdgcn_update_dpp(old, v, CTRL, 0xF, 0xF, BC);
}

// full-wave (64) sum; result broadcast to all lanes via readlane 63
__device__ __forceinline__ float wave_sum63(float v) {
    v += __int_as_float(dpp_i<0x111, true>(0, __float_as_int(v))); // row_shr:1
    v += __int_as_float(dpp_i<0x112, true>(0, __float_as_int(v))); // row_shr:2
    v += __int_as_float(dpp_i<0x114, true>(0, __float_as_int(v))); // row_shr:4
    v += __int_as_float(dpp_i<0x118, true>(0, __float_as_int(v))); // row_shr:8
    v += __int_as_float(dpp_i<0x142, true>(0, __float_as_int(v))); // row_bcast:15
    v += __int_as_float(dpp_i<0x143, true>(0, __float_as_int(v))); // row_bcast:31
    return __int_as_float(__builtin_amdgcn_readlane(__float_as_int(v), 63));
}

// full-wave max; result broadcast (uniform). bound_ctrl=false + old=v so
// out-of-range source lanes contribute fmax(v,v)=v.
__device__ __forceinline__ float wave_max63(float v) {
#define MX_STEP(C)                                                                    \
    {                                                                                 \
        int o = dpp_i<C, false>(__float_as_int(v), __float_as_int(v));                \
        v = fmaxf(v, __int_as_float(o));                                              \
    }
    MX_STEP(0x111) MX_STEP(0x112) MX_STEP(0x114) MX_STEP(0x118) MX_STEP(0x142) MX_STEP(0x143)
#undef MX_STEP
    return __int_as_float(__builtin_amdgcn_readlane(__float_as_int(v), 63));
}

// ---------- main kernel: one single-wave block per (row, part) unit ----------
// LDS (floats): tgt UV [0..63], tgt S [64..95], pred UV [96..159], pred S [160..191]
// UV layout: float4 j = (u_{2j}, u_{2j+1}, v_{2j}, v_{2j+1}); u=-2x, v=-2y, s=|pt|^2 (1e30 if invalid)
__global__ __launch_bounds__(64) void vltf_kernel(
    const float* __restrict__ pole_logits, const float* __restrict__ zero_logits,
    const float* __restrict__ poles_all,   const float* __restrict__ zeros_all,
    const float* __restrict__ tpoles,      const float* __restrict__ tzeros,
    const int* __restrict__ tnum_p,        const int* __restrict__ tnum_z,
    float* __restrict__ partials)
{
    __shared__ __align__(16) float myl[192];

    const int lane = threadIdx.x;     // 0..63
    const int unit = blockIdx.x;
    const int row  = unit >> 1;
    const int part = unit & 1;

    const float* logits = part ? zero_logits : pole_logits;
    const float* predp  = part ? zeros_all   : poles_all;
    const float* tgtp   = part ? tzeros      : tpoles;
    const int*   tnum   = part ? tnum_z      : tnum_p;

    // ---- cross-entropy + argmax over 33 logits (lanes 0..32 active) ----
    float x = (lane < NCNT) ? logits[row * NCNT + lane] : -FLT_MAX;
    float vmax = wave_max63(x);
    unsigned long long bm = __ballot(lane < NCNT && x == vmax);
    const int np = (int)__builtin_ctzll(bm);      // first-max index == pred count (uniform)
    float e = (lane < NCNT) ? __expf(x - vmax) : 0.f;
    float sume = wave_sum63(e);
    const int nt = tnum[row];                     // target count (uniform)
    float xt = __int_as_float(__builtin_amdgcn_readlane(__float_as_int(x), nt));
    float nll = vmax + __logf(sume) - xt;

    // ---- load own point; stage (u,v,s) for the other half ----
    const bool isPred = lane < 32;
    const int  idx    = lane & 31;
    const float2* ownArr = (const float2*)(isPred ? predp : tgtp);
    const float2  Pt     = ownArr[row * NPTS + idx];
    const int  nown = isPred ? np : nt;
    const bool vown = idx < nown;
    const float sreal = fmaf(Pt.x, Pt.x, Pt.y * Pt.y);

    const int wbase = isPred ? 96 : 0;
    const int uvpos = wbase + ((idx >> 1) << 2) + (idx & 1);
    myl[uvpos]            = vown ? -2.f * Pt.x : 0.f;
    myl[uvpos + 2]        = vown ? -2.f * Pt.y : 0.f;
    myl[wbase + 64 + idx] = vown ? sreal : 1e30f;
    __syncthreads();   // single-wave barrier: ~free, just orders LDS write->read

    // ---- chamfer: min over 32 "other" points, 4 points/iter via pk_fma ----
    const int rbase = isPred ? 0 : 96;            // pred lanes read tgt staging, tgt lanes read pred
    const float4* UVo = (const float4*)(myl + rbase);
    const float4* So  = (const float4*)(myl + rbase + 64);
    const f32x2 Pxv = mk2(Pt.x, Pt.x);
    const f32x2 Pyv = mk2(Pt.y, Pt.y);
    float m = FLT_MAX;
#pragma unroll
    for (int i = 0; i < 8; ++i) {
        float4 uv0 = UVo[2 * i], uv1 = UVo[2 * i + 1];
        float4 s4  = So[i];
        f32x2 val0 = Pyv * mk2(uv0.z, uv0.w) + mk2(s4.x, s4.y);
        val0       = Pxv * mk2(uv0.x, uv0.y) + val0;
        f32x2 val1 = Pyv * mk2(uv1.z, uv1.w) + mk2(s4.z, s4.w);
        val1       = Pxv * mk2(uv1.x, uv1.y) + val1;
        m = fminf(m, fminf(val0.x, val0.y));      // v_min3_f32
        m = fminf(m, fminf(val1.x, val1.y));
    }

    // ---- per-lane term with wave-uniform special cases ----
    float T;
    if (np > 0 && nt > 0) {
        // uniform reciprocal (1-ulp rcp; threshold is 0.925, error ~1e-7 here)
        float inv_n = __builtin_amdgcn_rcpf((float)nown);
        T = vown ? (m + sreal) * inv_n : 0.f;     // |p|^2 folded in once
    } else if (np == 0 && nt == 0) {
        T = 0.f;
    } else if (np == 0) {                          // out = sum_tgt_sq
        T = (!isPred && vown) ? sreal : 0.f;
    } else {                                       // nt == 0 -> sum_pred_sq
        T = (isPred && vown) ? sreal : 0.f;
    }
    float cham = wave_sum63(T);

    if (lane == 0) partials[unit] = 5.f * nll + cham;
}

// ---------- finalize: sum 65536 partials (as 16384 float4), divide by B ----------
__global__ __launch_bounds__(1024) void vltf_finalize(
    const float4* __restrict__ p4, int n4, float invB, float* __restrict__ out)
{
    float s = 0.f;
    for (int i = threadIdx.x; i < n4; i += 1024) {
        float4 v = p4[i];
        s += (v.x + v.y) + (v.z + v.w);
    }
    s = wave_sum63(s);
    __shared__ float sh[16];
    if ((threadIdx.x & 63) == 0) sh[threadIdx.x >> 6] = s;
    __syncthreads();
    if (threadIdx.x == 0) {
        float t = 0.f;
#pragma unroll
        for (int i = 0; i < 16; ++i) t += sh[i];
        out[0] = t * invB;
    }
}

extern "C" void kernel_launch(void* const* d_in, const int* in_sizes, int n_in,
                              void* d_out, int out_size, void* d_ws, size_t ws_size,
                              hipStream_t stream) {
    const float* pole_logits = (const float*)d_in[0];
    const float* zero_logits = (const float*)d_in[1];
    const float* poles_all   = (const float*)d_in[2];
    const float* zeros_all   = (const float*)d_in[3];
    const float* tpoles      = (const float*)d_in[4];
    const float* tzeros      = (const float*)d_in[5];
    const int*   tnp         = (const int*)d_in[6];
    const int*   tnz         = (const int*)d_in[7];

    const int B     = in_sizes[6];       // 32768
    const int units = 2 * B;             // (row, part) units; one single-wave block each

    float* partials = (float*)d_ws;      // units * 4 bytes (256 KiB) of scratch

    vltf_kernel<<<units, 64, 0, stream>>>(pole_logits, zero_logits,
                                          poles_all, zeros_all,
                                          tpoles, tzeros, tnp, tnz, partials);
    vltf_finalize<<<1, 1024, 0, stream>>>((const float4*)partials, units / 4,
                                          1.0f / (float)B, (float*)d_out);
}